// Round 11
// baseline (279.819 us; speedup 1.0000x reference)
//
#include <hip/hip_runtime.h>
#include <hip/hip_bf16.h>

// ChunkwiseRetentionMixer: state = x@Ws^T ; state = cumsum_L(state) ;
// out = rmsnorm(state)@Wo^T.  B=4, L=8192, H=1024, S=64, fp32 in/out.
//
// R10 = R5 resubmitted (infra failures rounds 0-10): triple-split bf16 MFMA
// (x = hi + mid + lo, 6 products, fp32 accum).  Dropped terms <= 3*2^-24
// relative -> fp32-equivalent accuracy.
//   k_proj: 64x64x1024 GEMM -> state [c][l][s] + chunk col-sums
//   k_scan: wave-shuffle scan of chunk sums -> exclusive offsets
//   k_out : in-chunk shuffle scan (+rms scale folded into split) +
//           64x1024x64 GEMM, write out.

#define BB 4
#define LL 8192
#define HH 1024
#define SS 64
#define TL 64
#define CPB (LL / TL)          // 128 chunks per batch
#define NCHUNK (BB * CPB)      // 512
#define EPS 1.1920928955078125e-07f

typedef __attribute__((ext_vector_type(8))) short bf16x8;   // 8 bf16 = 4 VGPRs
typedef __attribute__((ext_vector_type(4))) float f32x4;    // MFMA accum

__device__ __forceinline__ short bf16h(float v) {
    __hip_bfloat16 b = __float2bfloat16(v);
    return __builtin_bit_cast(short, b);
}
__device__ __forceinline__ float bf16tof(short s) {
    __hip_bfloat16 b = __builtin_bit_cast(__hip_bfloat16, s);
    return __bfloat162float(b);
}

// ---- 64x64 fp32 tile staging, split into load (global->reg) and write
// (3-level bf16 split + reg->LDS) so next-tile loads overlap compute.
// Thread t covers rows {t>>3, 32+(t>>3)}, k = (t&7)*8 .. +7  (coalesced).
__device__ __forceinline__ void stage_load(const float* __restrict__ src, int rstride,
                                           int tid, float4* v) {
    #pragma unroll
    for (int it = 0; it < 2; ++it) {
        const int row = it * 32 + (tid >> 3);
        const int k = (tid & 7) * 8;
        const float* p = src + (long)row * rstride + k;
        v[it * 2 + 0] = *(const float4*)p;
        v[it * 2 + 1] = *(const float4*)(p + 4);
    }
}
__device__ __forceinline__ void stage_write3(const float4* v, short (*th)[72],
                                             short (*tm)[72], short (*tl)[72], int tid) {
    #pragma unroll
    for (int it = 0; it < 2; ++it) {
        const int row = it * 32 + (tid >> 3);
        const int k = (tid & 7) * 8;
        const float f[8] = {v[it*2].x, v[it*2].y, v[it*2].z, v[it*2].w,
                            v[it*2+1].x, v[it*2+1].y, v[it*2+1].z, v[it*2+1].w};
        bf16x8 h8, m8, l8;
        #pragma unroll
        for (int j = 0; j < 8; ++j) {
            const short hb = bf16h(f[j]);
            const float r1 = f[j] - bf16tof(hb);     // exact in fp32
            const short mb = bf16h(r1);
            const float r2 = r1 - bf16tof(mb);       // exact in fp32
            h8[j] = hb; m8[j] = mb; l8[j] = bf16h(r2);
        }
        *(bf16x8*)&th[row][k] = h8;
        *(bf16x8*)&tm[row][k] = m8;
        *(bf16x8*)&tl[row][k] = l8;
    }
}

// 6-product accumulate: (h+m+l)*(h+m+l) keeping terms >= 2^-24 scale
#define MFMA6(ACC, AH, AM, AL, BH, BM, BL)                                        \
    ACC = __builtin_amdgcn_mfma_f32_16x16x32_bf16(AH, BH, ACC, 0, 0, 0);          \
    ACC = __builtin_amdgcn_mfma_f32_16x16x32_bf16(AH, BM, ACC, 0, 0, 0);          \
    ACC = __builtin_amdgcn_mfma_f32_16x16x32_bf16(AM, BH, ACC, 0, 0, 0);          \
    ACC = __builtin_amdgcn_mfma_f32_16x16x32_bf16(AH, BL, ACC, 0, 0, 0);          \
    ACC = __builtin_amdgcn_mfma_f32_16x16x32_bf16(AL, BH, ACC, 0, 0, 0);          \
    ACC = __builtin_amdgcn_mfma_f32_16x16x32_bf16(AM, BM, ACC, 0, 0, 0);

// ============================ k_proj ============================
__global__ __launch_bounds__(256) void k_proj(const float* __restrict__ x,
                                              const float* __restrict__ Ws,
                                              float* __restrict__ state,  // [c][l][s]
                                              float* __restrict__ csum)   // [c][s]
{
    __shared__ __align__(16) short Ah[64][72], Am[64][72], Al[64][72];
    __shared__ __align__(16) short Bh[64][72], Bm[64][72], Bl[64][72];
    float (*red)[65] = (float(*)[65])Ah;    // overlay: used only after last K-tile

    const int tid = threadIdx.x;
    const int lane = tid & 63, w = tid >> 6;
    const int l16 = lane & 15, lg = lane >> 4;
    const int wr = w >> 1, wc = w & 1;      // wave -> 32x32 output quadrant
    const int c = blockIdx.x;
    const float* xp = x + (long)c * TL * HH;

    f32x4 acc[2][2] = {};
    float4 va[4], vb[4];
    stage_load(xp, HH, tid, va);
    stage_load(Ws, HH, tid, vb);

    for (int kt = 0; kt < HH; kt += 64) {
        stage_write3(va, Ah, Am, Al, tid);
        stage_write3(vb, Bh, Bm, Bl, tid);
        __syncthreads();                            // tiles ready
        if (kt + 64 < HH) {                         // prefetch next K-tile
            stage_load(xp + kt + 64, HH, tid, va);
            stage_load(Ws + kt + 64, HH, tid, vb);
        }
        #pragma unroll
        for (int ks = 0; ks < 2; ++ks) {
            bf16x8 ah[2], am[2], al[2], bh[2], bm[2], bl[2];
            #pragma unroll
            for (int f = 0; f < 2; ++f) {
                const int ar = wr*32 + f*16 + l16, br = wc*32 + f*16 + l16;
                const int ko = ks*32 + lg*8;
                ah[f] = *(const bf16x8*)&Ah[ar][ko];
                am[f] = *(const bf16x8*)&Am[ar][ko];
                al[f] = *(const bf16x8*)&Al[ar][ko];
                bh[f] = *(const bf16x8*)&Bh[br][ko];
                bm[f] = *(const bf16x8*)&Bm[br][ko];
                bl[f] = *(const bf16x8*)&Bl[br][ko];
            }
            #pragma unroll
            for (int fi = 0; fi < 2; ++fi)
                #pragma unroll
                for (int fj = 0; fj < 2; ++fj) {
                    MFMA6(acc[fi][fj], ah[fi], am[fi], al[fi], bh[fj], bm[fj], bl[fj])
                }
        }
        __syncthreads();                            // tiles consumed
    }

    // epilogue: D[l][s] with l = wr*32+fi*16+lg*4+r, s = wc*32+fj*16+l16
    float* sp = state + (long)c * (TL * SS);
    #pragma unroll
    for (int fi = 0; fi < 2; ++fi)
        #pragma unroll
        for (int fj = 0; fj < 2; ++fj) {
            float part = 0.f;
            #pragma unroll
            for (int r = 0; r < 4; ++r) {
                const int l = wr*32 + fi*16 + lg*4 + r;
                const int s = wc*32 + fj*16 + l16;
                sp[l * SS + s] = acc[fi][fj][r];
                part += acc[fi][fj][r];
            }
            red[(wr*2 + fi)*4 + lg][wc*32 + fj*16 + l16] = part;
        }
    __syncthreads();
    if (tid < 64) {
        float t = 0.f;
        #pragma unroll
        for (int g = 0; g < 16; ++g) t += red[g][tid];
        csum[(long)c * SS + tid] = t;
    }
}

// ============================ k_scan ============================
__global__ __launch_bounds__(256) void k_scan(const float* __restrict__ csum,
                                              float* __restrict__ off)
{
    const int tid = threadIdx.x;
    const int lane = tid & 63;
    const int wid = (blockIdx.x * 256 + tid) >> 6;  // 0..255
    const int b = wid >> 6, s = wid & 63;
    const long base = (long)b * CPB * SS + s;

    float i0 = csum[base + (long)lane * SS];
    float i1 = csum[base + (long)(lane + 64) * SS];
    #pragma unroll
    for (int d = 1; d < 64; d <<= 1) {
        float n = __shfl_up(i0, d, 64); if (lane >= d) i0 += n;
    }
    #pragma unroll
    for (int d = 1; d < 64; d <<= 1) {
        float n = __shfl_up(i1, d, 64); if (lane >= d) i1 += n;
    }
    float tot0 = __shfl(i0, 63, 64);
    float e0 = __shfl_up(i0, 1, 64); if (lane == 0) e0 = 0.f;
    float e1 = __shfl_up(i1, 1, 64); if (lane == 0) e1 = 0.f;
    e1 += tot0;
    off[base + (long)lane * SS] = e0;
    off[base + (long)(lane + 64) * SS] = e1;
}

// ============================ k_out ============================
__global__ __launch_bounds__(256) void k_out(const float* __restrict__ state, // [c][l][s]
                                             const float* __restrict__ off,   // [c][s]
                                             const float* __restrict__ Wo,    // [h][s]
                                             float* __restrict__ out)         // [b][l][h]
{
    __shared__ __align__(16) short Ah[64][72], Am[64][72], Al[64][72];
    __shared__ __align__(16) char pool[64 * 72 * 2 * 3];   // 27648 B: B 3-tiles | st
    __shared__ float ssq[4][64];
    __shared__ float scale[64];
    float (*st)[65] = (float(*)[65])pool;                  // 16640 B, dies after Phase C
    short (*Bh)[72] = (short(*)[72])pool;
    short (*Bm)[72] = (short(*)[72])(pool + 64 * 72 * 2);
    short (*Bl)[72] = (short(*)[72])(pool + 64 * 72 * 4);

    const int tid = threadIdx.x;
    const int lane = tid & 63, w = tid >> 6;
    const int l16 = lane & 15, lg = lane >> 4;
    const int wr = w >> 1, wc = w & 1;
    const int c = blockIdx.x;

    float4 vw[4];
    stage_load(Wo, SS, tid, vw);                 // prefetch first Wo tile early

    // Phase A: state tile -> st[l][s] (stride 65: scan column reads 2-way free)
    const float* sp = state + (long)c * (TL * SS);
    #pragma unroll
    for (int i = 0; i < 4; ++i) {
        const int e = (i * 256 + tid) * 4;
        const int l = e >> 6, s = e & 63;
        const float4 v = *(const float4*)(sp + e);
        st[l][s] = v.x; st[l][s+1] = v.y; st[l][s+2] = v.z; st[l][s+3] = v.w;
    }
    __syncthreads();

    // Phase B: shuffle-scan along l (lane = l), wave w owns s = w*16..+15;
    // fused per-row sum-of-squares.
    float sq = 0.f;
    for (int i = 0; i < 16; ++i) {
        const int s = w * 16 + i;
        float v = st[lane][s];
        #pragma unroll
        for (int d = 1; d < 64; d <<= 1) {
            const float n = __shfl_up(v, d, 64);
            if (lane >= d) v += n;
        }
        v += off[(long)c * SS + s];
        st[lane][s] = v;
        sq = fmaf(v, v, sq);
    }
    ssq[w][lane] = sq;
    __syncthreads();
    if (tid < 64) {
        const float t = ssq[0][tid] + ssq[1][tid] + ssq[2][tid] + ssq[3][tid];
        scale[tid] = rsqrtf(t * (1.f / 64.f) + EPS);
    }
    __syncthreads();

    // Phase C: rms-scale rows, 3-level split to bf16 A-tiles (scale folded here)
    {
        const int l = tid >> 2, s0 = (tid & 3) * 16;
        const float sc = scale[l];
        #pragma unroll
        for (int blk = 0; blk < 2; ++blk) {
            bf16x8 h8, m8, l8;
            #pragma unroll
            for (int j = 0; j < 8; ++j) {
                const float v = st[l][s0 + blk*8 + j] * sc;
                const short hb = bf16h(v);
                const float r1 = v - bf16tof(hb);
                const short mb = bf16h(r1);
                const float r2 = r1 - bf16tof(mb);
                h8[j] = hb; m8[j] = mb; l8[j] = bf16h(r2);
            }
            *(bf16x8*)&Ah[l][s0 + blk*8] = h8;
            *(bf16x8*)&Am[l][s0 + blk*8] = m8;
            *(bf16x8*)&Al[l][s0 + blk*8] = l8;
        }
    }
    __syncthreads();                              // st dead from here; pool -> B tiles

    // hoist A-frags: reused across all 16 h-tiles
    bf16x8 ah[2][2], am[2][2], al[2][2];          // [fi][ks]
    #pragma unroll
    for (int f = 0; f < 2; ++f)
        #pragma unroll
        for (int ks = 0; ks < 2; ++ks) {
            const int ar = wr*32 + f*16 + l16, ko = ks*32 + lg*8;
            ah[f][ks] = *(const bf16x8*)&Ah[ar][ko];
            am[f][ks] = *(const bf16x8*)&Am[ar][ko];
            al[f][ks] = *(const bf16x8*)&Al[ar][ko];
        }

    const int b = c / CPB;
    const int l0 = (c % CPB) * TL;
    float* op = out + ((long)b * LL + l0) * HH;

    for (int ht = 0; ht < HH; ht += 64) {
        stage_write3(vw, Bh, Bm, Bl, tid);
        __syncthreads();                          // B tile ready
        if (ht + 64 < HH)
            stage_load(Wo + (long)(ht + 64) * SS, SS, tid, vw);
        f32x4 acc[2][2] = {};
        #pragma unroll
        for (int ks = 0; ks < 2; ++ks) {
            bf16x8 bh[2], bm[2], bl[2];
            #pragma unroll
            for (int f = 0; f < 2; ++f) {
                const int br = wc*32 + f*16 + l16, ko = ks*32 + lg*8;
                bh[f] = *(const bf16x8*)&Bh[br][ko];
                bm[f] = *(const bf16x8*)&Bm[br][ko];
                bl[f] = *(const bf16x8*)&Bl[br][ko];
            }
            #pragma unroll
            for (int fi = 0; fi < 2; ++fi)
                #pragma unroll
                for (int fj = 0; fj < 2; ++fj) {
                    MFMA6(acc[fi][fj], ah[fi][ks], am[fi][ks], al[fi][ks],
                          bh[fj], bm[fj], bl[fj])
                }
        }
        #pragma unroll
        for (int fi = 0; fi < 2; ++fi)
            #pragma unroll
            for (int fj = 0; fj < 2; ++fj)
                #pragma unroll
                for (int r = 0; r < 4; ++r) {
                    const int l = wr*32 + fi*16 + lg*4 + r;
                    const int h = wc*32 + fj*16 + l16;
                    op[(long)l * HH + ht + h] = acc[fi][fj][r];
                }
        __syncthreads();                          // B tile consumed
    }
}

extern "C" void kernel_launch(void* const* d_in, const int* in_sizes, int n_in,
                              void* d_out, int out_size, void* d_ws, size_t ws_size,
                              hipStream_t stream) {
    const float* x  = (const float*)d_in[0];
    const float* Ws = (const float*)d_in[1];
    const float* Wo = (const float*)d_in[2];
    float* out = (float*)d_out;

    float* state = (float*)d_ws;                               // 8 MB
    float* csum  = state + (size_t)NCHUNK * SS * TL;           // 128 KB
    float* off   = csum + (size_t)NCHUNK * SS;                 // 128 KB

    k_proj<<<NCHUNK, 256, 0, stream>>>(x, Ws, state, csum);
    k_scan<<<64, 256, 0, stream>>>(csum, off);
    k_out<<<NCHUNK, 256, 0, stream>>>(state, off, Wo, out);
}

// Round 12
// 276.655 us; speedup vs baseline: 1.0114x; 1.0114x over previous
//
#include <hip/hip_runtime.h>
#include <hip/hip_bf16.h>

// ChunkwiseRetentionMixer: state = x@Ws^T ; state = cumsum_L(state) ;
// out = rmsnorm(state)@Wo^T.  B=4, L=8192, H=1024, S=64, fp32 in/out.
//
// R11: first bench landed (R10: PASS, absmax 0.03125, dur 280us; kernels
// ~158us, 3x model, limiter = 2 waves/SIMD + staging VALU + barrier serial).
// This round: 512-thread blocks (8 waves -> 4 waves/SIMD), weights pre-split
// ONCE by k_prep (B-staging becomes pure copy), numerics bit-identical
// triple-split bf16 MFMA (6 products, fp32 accum).

#define BB 4
#define LL 8192
#define HH 1024
#define SS 64
#define TL 64
#define CPB (LL / TL)          // 128 chunks per batch
#define NCHUNK (BB * CPB)      // 512
#define EPS 1.1920928955078125e-07f

typedef __attribute__((ext_vector_type(8))) short bf16x8;   // 8 bf16 = 4 VGPRs
typedef __attribute__((ext_vector_type(4))) float f32x4;    // MFMA accum

__device__ __forceinline__ short bf16h(float v) {
    __hip_bfloat16 b = __float2bfloat16(v);
    return __builtin_bit_cast(short, b);
}
__device__ __forceinline__ float bf16tof(short s) {
    __hip_bfloat16 b = __builtin_bit_cast(__hip_bfloat16, s);
    return __bfloat162float(b);
}

__device__ __forceinline__ void split3_8(const float* f, bf16x8& h8, bf16x8& m8, bf16x8& l8) {
    #pragma unroll
    for (int j = 0; j < 8; ++j) {
        const short hb = bf16h(f[j]);
        const float r1 = f[j] - bf16tof(hb);     // exact in fp32
        const short mb = bf16h(r1);
        const float r2 = r1 - bf16tof(mb);       // exact in fp32
        h8[j] = hb; m8[j] = mb; l8[j] = bf16h(r2);
    }
}

// 6-product accumulate: (h+m+l)*(h+m+l) keeping terms >= 2^-24 scale
#define MFMA6(ACC, AH, AM, AL, BH, BM, BL)                                        \
    ACC = __builtin_amdgcn_mfma_f32_16x16x32_bf16(AH, BH, ACC, 0, 0, 0);          \
    ACC = __builtin_amdgcn_mfma_f32_16x16x32_bf16(AH, BM, ACC, 0, 0, 0);          \
    ACC = __builtin_amdgcn_mfma_f32_16x16x32_bf16(AM, BH, ACC, 0, 0, 0);          \
    ACC = __builtin_amdgcn_mfma_f32_16x16x32_bf16(AH, BL, ACC, 0, 0, 0);          \
    ACC = __builtin_amdgcn_mfma_f32_16x16x32_bf16(AL, BH, ACC, 0, 0, 0);          \
    ACC = __builtin_amdgcn_mfma_f32_16x16x32_bf16(AM, BM, ACC, 0, 0, 0);

// ===================== k_prep: split Ws, Wo once =====================
__global__ __launch_bounds__(512) void k_prep(const float* __restrict__ Ws,
                                              const float* __restrict__ Wo,
                                              short* __restrict__ wsh, short* __restrict__ wsm,
                                              short* __restrict__ wsl, short* __restrict__ woh,
                                              short* __restrict__ wom, short* __restrict__ wol)
{
    const int i = blockIdx.x * 512 + threadIdx.x;   // 0..65535
    {
        const float v = Ws[i];
        const short h = bf16h(v); const float r1 = v - bf16tof(h);
        const short m = bf16h(r1); const float r2 = r1 - bf16tof(m);
        wsh[i] = h; wsm[i] = m; wsl[i] = bf16h(r2);
    }
    {
        const float v = Wo[i];
        const short h = bf16h(v); const float r1 = v - bf16tof(h);
        const short m = bf16h(r1); const float r2 = r1 - bf16tof(m);
        woh[i] = h; wom[i] = m; wol[i] = bf16h(r2);
    }
}

// ============================ k_proj ============================
// 512 threads = 8 waves; wave w -> rows wr*32..+31 (wr=w>>2), cols wc*16..+15.
__global__ __launch_bounds__(512, 4) void k_proj(const float* __restrict__ x,
                                                 const short* __restrict__ wsh,
                                                 const short* __restrict__ wsm,
                                                 const short* __restrict__ wsl,
                                                 float* __restrict__ state,  // [c][l][s]
                                                 float* __restrict__ csum)   // [c][s]
{
    __shared__ __align__(16) short Ah[64][72], Am[64][72], Al[64][72];
    __shared__ __align__(16) short Bh[64][72], Bm[64][72], Bl[64][72];
    float (*red)[65] = (float(*)[65])Ah;    // overlay: used only after last K-tile

    const int tid = threadIdx.x;
    const int lane = tid & 63, w = tid >> 6;
    const int l16 = lane & 15, lg = lane >> 4;
    const int wr = w >> 2, wc = w & 3;
    const int c = blockIdx.x;
    const int arow = tid >> 3, acol8 = (tid & 7) * 8;   // staging map: 64x64 once
    const float* xp = x + (long)c * TL * HH;

    f32x4 acc[2] = {};
    float4 va[2]; bf16x8 vb[3];
    va[0] = *(const float4*)(xp + (long)arow * HH + acol8);
    va[1] = *(const float4*)(xp + (long)arow * HH + acol8 + 4);
    vb[0] = *(const bf16x8*)(wsh + arow * HH + acol8);
    vb[1] = *(const bf16x8*)(wsm + arow * HH + acol8);
    vb[2] = *(const bf16x8*)(wsl + arow * HH + acol8);

    for (int kt = 0; kt < HH; kt += 64) {
        {   // A: split fp32 -> 3 bf16 levels; B: pure copy of pre-split
            const float f8[8] = {va[0].x, va[0].y, va[0].z, va[0].w,
                                 va[1].x, va[1].y, va[1].z, va[1].w};
            bf16x8 h8, m8, l8;
            split3_8(f8, h8, m8, l8);
            *(bf16x8*)&Ah[arow][acol8] = h8;
            *(bf16x8*)&Am[arow][acol8] = m8;
            *(bf16x8*)&Al[arow][acol8] = l8;
            *(bf16x8*)&Bh[arow][acol8] = vb[0];
            *(bf16x8*)&Bm[arow][acol8] = vb[1];
            *(bf16x8*)&Bl[arow][acol8] = vb[2];
        }
        __syncthreads();                            // tiles ready
        if (kt + 64 < HH) {                         // prefetch next K-tile
            va[0] = *(const float4*)(xp + (long)arow * HH + kt + 64 + acol8);
            va[1] = *(const float4*)(xp + (long)arow * HH + kt + 64 + acol8 + 4);
            vb[0] = *(const bf16x8*)(wsh + arow * HH + kt + 64 + acol8);
            vb[1] = *(const bf16x8*)(wsm + arow * HH + kt + 64 + acol8);
            vb[2] = *(const bf16x8*)(wsl + arow * HH + kt + 64 + acol8);
        }
        #pragma unroll
        for (int ks = 0; ks < 2; ++ks) {
            const int ko = ks * 32 + lg * 8;
            bf16x8 ah[2], am[2], al[2];
            #pragma unroll
            for (int f = 0; f < 2; ++f) {
                const int ar = wr * 32 + f * 16 + l16;
                ah[f] = *(const bf16x8*)&Ah[ar][ko];
                am[f] = *(const bf16x8*)&Am[ar][ko];
                al[f] = *(const bf16x8*)&Al[ar][ko];
            }
            const int br = wc * 16 + l16;
            const bf16x8 bh = *(const bf16x8*)&Bh[br][ko];
            const bf16x8 bm = *(const bf16x8*)&Bm[br][ko];
            const bf16x8 bl = *(const bf16x8*)&Bl[br][ko];
            #pragma unroll
            for (int fi = 0; fi < 2; ++fi) {
                MFMA6(acc[fi], ah[fi], am[fi], al[fi], bh, bm, bl)
            }
        }
        __syncthreads();                            // tiles consumed
    }

    // epilogue: D row l = wr*32+fi*16+lg*4+r, col s = wc*16+l16
    float* sp = state + (long)c * (TL * SS);
    #pragma unroll
    for (int fi = 0; fi < 2; ++fi) {
        float part = 0.f;
        #pragma unroll
        for (int r = 0; r < 4; ++r) {
            const int l = wr * 32 + fi * 16 + lg * 4 + r;
            const int s = wc * 16 + l16;
            sp[l * SS + s] = acc[fi][r];
            part += acc[fi][r];
        }
        red[(wr * 2 + fi) * 4 + lg][wc * 16 + l16] = part;
    }
    __syncthreads();
    if (tid < 64) {
        float t = 0.f;
        #pragma unroll
        for (int g = 0; g < 16; ++g) t += red[g][tid];
        csum[(long)c * SS + tid] = t;
    }
}

// ============================ k_scan ============================
__global__ __launch_bounds__(256) void k_scan(const float* __restrict__ csum,
                                              float* __restrict__ off)
{
    const int tid = threadIdx.x;
    const int lane = tid & 63;
    const int wid = (blockIdx.x * 256 + tid) >> 6;  // 0..255
    const int b = wid >> 6, s = wid & 63;
    const long base = (long)b * CPB * SS + s;

    float i0 = csum[base + (long)lane * SS];
    float i1 = csum[base + (long)(lane + 64) * SS];
    #pragma unroll
    for (int d = 1; d < 64; d <<= 1) {
        float n = __shfl_up(i0, d, 64); if (lane >= d) i0 += n;
    }
    #pragma unroll
    for (int d = 1; d < 64; d <<= 1) {
        float n = __shfl_up(i1, d, 64); if (lane >= d) i1 += n;
    }
    float tot0 = __shfl(i0, 63, 64);
    float e0 = __shfl_up(i0, 1, 64); if (lane == 0) e0 = 0.f;
    float e1 = __shfl_up(i1, 1, 64); if (lane == 0) e1 = 0.f;
    e1 += tot0;
    off[base + (long)lane * SS] = e0;
    off[base + (long)(lane + 64) * SS] = e1;
}

// ============================ k_out ============================
__global__ __launch_bounds__(512, 4) void k_out(const float* __restrict__ state, // [c][l][s]
                                                const float* __restrict__ off,   // [c][s]
                                                const short* __restrict__ woh,   // [h][s] presplit
                                                const short* __restrict__ wom,
                                                const short* __restrict__ wol,
                                                float* __restrict__ out)         // [b][l][h]
{
    __shared__ __align__(16) short Ah[64][72], Am[64][72], Al[64][72];
    __shared__ __align__(16) char pool[64 * 72 * 2 * 3];   // 27648 B: B 3-tiles | st
    __shared__ float ssq[8][64];
    __shared__ float scale[64];
    float (*st)[65] = (float(*)[65])pool;                  // 16640 B, dies after Phase C
    short (*Bh)[72] = (short(*)[72])pool;
    short (*Bm)[72] = (short(*)[72])(pool + 64 * 72 * 2);
    short (*Bl)[72] = (short(*)[72])(pool + 64 * 72 * 4);

    const int tid = threadIdx.x;
    const int lane = tid & 63, w = tid >> 6;
    const int l16 = lane & 15, lg = lane >> 4;
    const int wr = w >> 2, wc = w & 3;
    const int c = blockIdx.x;
    const int arow = tid >> 3, acol8 = (tid & 7) * 8;

    // prefetch first Wo tile (pure copy of pre-split)
    bf16x8 vw[3];
    vw[0] = *(const bf16x8*)(woh + arow * SS + acol8);
    vw[1] = *(const bf16x8*)(wom + arow * SS + acol8);
    vw[2] = *(const bf16x8*)(wol + arow * SS + acol8);

    // Phase A: state tile -> st[l][s] (stride 65)
    const float* sp = state + (long)c * (TL * SS);
    #pragma unroll
    for (int i = 0; i < 2; ++i) {
        const int e = (i * 512 + tid) * 4;
        const int l = e >> 6, s = e & 63;
        const float4 v = *(const float4*)(sp + e);
        st[l][s] = v.x; st[l][s+1] = v.y; st[l][s+2] = v.z; st[l][s+3] = v.w;
    }
    __syncthreads();

    // Phase B: shuffle-scan along l (lane = l), wave w owns s = w*8..+7;
    // fused per-row sum-of-squares.
    float sq = 0.f;
    for (int i = 0; i < 8; ++i) {
        const int s = w * 8 + i;
        float v = st[lane][s];
        #pragma unroll
        for (int d = 1; d < 64; d <<= 1) {
            const float n = __shfl_up(v, d, 64);
            if (lane >= d) v += n;
        }
        v += off[(long)c * SS + s];
        st[lane][s] = v;
        sq = fmaf(v, v, sq);
    }
    ssq[w][lane] = sq;
    __syncthreads();
    if (tid < 64) {
        float t = 0.f;
        #pragma unroll
        for (int g = 0; g < 8; ++g) t += ssq[g][tid];
        scale[tid] = rsqrtf(t * (1.f / 64.f) + EPS);
    }
    __syncthreads();

    // Phase C: rms-scale rows, 3-level split to bf16 A-tiles (scale folded)
    {
        const int l = tid >> 3, s0 = (tid & 7) * 8;
        const float sc = scale[l];
        float f8[8];
        #pragma unroll
        for (int j = 0; j < 8; ++j) f8[j] = st[l][s0 + j] * sc;
        bf16x8 h8, m8, l8;
        split3_8(f8, h8, m8, l8);
        *(bf16x8*)&Ah[l][s0] = h8;
        *(bf16x8*)&Am[l][s0] = m8;
        *(bf16x8*)&Al[l][s0] = l8;
    }
    __syncthreads();                              // st dead; pool -> B tiles

    const int b = c / CPB;
    const int l0 = (c % CPB) * TL;
    float* op = out + ((long)b * LL + l0) * HH;

    for (int ht = 0; ht < HH; ht += 64) {
        *(bf16x8*)&Bh[arow][acol8] = vw[0];
        *(bf16x8*)&Bm[arow][acol8] = vw[1];
        *(bf16x8*)&Bl[arow][acol8] = vw[2];
        __syncthreads();                          // B tile ready
        if (ht + 64 < HH) {
            vw[0] = *(const bf16x8*)(woh + (ht + 64 + arow) * SS + acol8);
            vw[1] = *(const bf16x8*)(wom + (ht + 64 + arow) * SS + acol8);
            vw[2] = *(const bf16x8*)(wol + (ht + 64 + arow) * SS + acol8);
        }
        f32x4 acc[2] = {};
        #pragma unroll
        for (int ks = 0; ks < 2; ++ks) {
            const int ko = ks * 32 + lg * 8;
            const int br = wc * 16 + l16;
            const bf16x8 bh = *(const bf16x8*)&Bh[br][ko];
            const bf16x8 bm = *(const bf16x8*)&Bm[br][ko];
            const bf16x8 bl = *(const bf16x8*)&Bl[br][ko];
            bf16x8 ah[2], am[2], al[2];
            #pragma unroll
            for (int f = 0; f < 2; ++f) {
                const int ar = wr * 32 + f * 16 + l16;
                ah[f] = *(const bf16x8*)&Ah[ar][ko];
                am[f] = *(const bf16x8*)&Am[ar][ko];
                al[f] = *(const bf16x8*)&Al[ar][ko];
            }
            #pragma unroll
            for (int fi = 0; fi < 2; ++fi) {
                MFMA6(acc[fi], ah[fi], am[fi], al[fi], bh, bm, bl)
            }
        }
        #pragma unroll
        for (int fi = 0; fi < 2; ++fi)
            #pragma unroll
            for (int r = 0; r < 4; ++r) {
                const int l = wr * 32 + fi * 16 + lg * 4 + r;
                const int h = wc * 16 + l16;
                op[(long)l * HH + ht + h] = acc[fi][r];
            }
        __syncthreads();                          // B tile consumed
    }
}

extern "C" void kernel_launch(void* const* d_in, const int* in_sizes, int n_in,
                              void* d_out, int out_size, void* d_ws, size_t ws_size,
                              hipStream_t stream) {
    const float* x  = (const float*)d_in[0];
    const float* Ws = (const float*)d_in[1];
    const float* Wo = (const float*)d_in[2];
    float* out = (float*)d_out;

    float* state = (float*)d_ws;                               // 8 MB
    float* csum  = state + (size_t)NCHUNK * SS * TL;           // 128 KB
    float* off   = csum + (size_t)NCHUNK * SS;                 // 128 KB
    short* wsh = (short*)(off + (size_t)NCHUNK * SS);          // 6 x 128 KB bf16
    short* wsm = wsh + (size_t)SS * HH;
    short* wsl = wsm + (size_t)SS * HH;
    short* woh = wsl + (size_t)SS * HH;
    short* wom = woh + (size_t)HH * SS;
    short* wol = wom + (size_t)HH * SS;

    k_prep<<<128, 512, 0, stream>>>(Ws, Wo, wsh, wsm, wsl, woh, wom, wol);
    k_proj<<<NCHUNK, 512, 0, stream>>>(x, wsh, wsm, wsl, state, csum);
    k_scan<<<64, 256, 0, stream>>>(csum, off);
    k_out<<<NCHUNK, 512, 0, stream>>>(state, off, woh, wom, wol, out);
}